// Round 2
// baseline (248.261 us; speedup 1.0000x reference)
//
#include <hip/hip_runtime.h>

// Forward kinematics, H36M 17-joint skeleton.
// One thread = one sample.
// R5 change: halve the LDS staging footprint to lift the occupancy cap.
// R4 post-mortem: VGPR=68 in BOTH r0 and r4 proves the 16 float4 input loads
// were ALREADY batched (64 live load-result floats + addressing); the
// sched_barrier was a no-op for batching and cost 8% -> reverted.
// Real binder: LDS 26112 B/block -> 6 blocks/CU -> 12 waves/CU cap, measured
// occupancy 25%, wave lifetime ~45k cyc vs ~2.6k VALU cyc => latency-bound.
// Fix: stage output in two per-sample chunks reusing ONE 128x27 buffer:
//   phase A = joints 0..8  (27 floats, root + bones 0..7)
//   phase B = joints 9..16 (24 floats, bones 8..15; stride kept 27 = odd)
// LDS 13824 B -> 11 blocks/CU -> 22 waves/CU. Stores become dword-granular
// over contiguous runs of 27/24 floats (magic-div map, ~2-3 segments per
// 64-lane store) -- near-coalesced, WRITE_SIZE should stay ~exact.

#define NB 128
#define CA 27  // chunk A floats/sample (joints 0..8), also LDS stride
#define CB 24  // chunk B floats/sample (joints 9..16)

__device__ __forceinline__ void mm3(const float A[9], const float B[9], float C[9]) {
#pragma unroll
    for (int r = 0; r < 3; ++r) {
        C[3*r+0] = A[3*r+0]*B[0] + A[3*r+1]*B[3] + A[3*r+2]*B[6];
        C[3*r+1] = A[3*r+0]*B[1] + A[3*r+1]*B[4] + A[3*r+2]*B[7];
        C[3*r+2] = A[3*r+0]*B[2] + A[3*r+1]*B[5] + A[3*r+2]*B[8];
    }
}

// R = Rx(a) @ Ry(b) @ Rz(c)  (pytorch3d euler_angles_to_matrix 'XYZ'), row-major
__device__ __forceinline__ void euler_rot(const float* __restrict__ ev, int i, float R[9]) {
    float a = ev[3*i+0], b = ev[3*i+1], c = ev[3*i+2];
    float sx, cx, sy, cy, sz, cz;
    __sincosf(a, &sx, &cx);
    __sincosf(b, &sy, &cy);
    __sincosf(c, &sz, &cz);
    R[0] = cy*cz;             R[1] = -cy*sz;            R[2] = sy;
    R[3] = sx*sy*cz + cx*sz;  R[4] = -sx*sy*sz + cx*cz; R[5] = -sx*cy;
    R[6] = -cx*sy*cz + sx*sz; R[7] = cx*sy*sz + sx*cz;  R[8] = cx*cy;
}

__global__ void __launch_bounds__(NB)
fk17_kernel(const float* __restrict__ euler, const float* __restrict__ blen,
            float* __restrict__ out, int n)
{
    __shared__ float s_o[NB * CA];  // 13824 B, odd stride -> conflict-free

    const int tid    = threadIdx.x;
    const int block0 = blockIdx.x * NB;
    const int nvalid = min(NB, n - block0);
    const int t      = block0 + tid;

    float ev[48];
    float L[16];
    float M8[9];
    float p8x, p8y, p8z;

    // ================= phase A: joints 0..8 =================
    if (tid < nvalid) {
        const float4* ge4 = (const float4*)(euler + (size_t)t * 48);
        const float4* gb4 = (const float4*)(blen + (size_t)t * 16);
#pragma unroll
        for (int q = 0; q < 12; ++q) {
            float4 v = ge4[q];
            ev[4*q+0] = v.x; ev[4*q+1] = v.y; ev[4*q+2] = v.z; ev[4*q+3] = v.w;
        }
#pragma unroll
        for (int q = 0; q < 4; ++q) {
            float4 v = gb4[q];
            L[4*q+0] = v.x; L[4*q+1] = v.y; L[4*q+2] = v.z; L[4*q+3] = v.w;
        }

        float* o = s_o + tid * CA;
        float Ma[9], Mb[9], R[9];
        float px, py, pz;

        // root (joint 0)
        o[0] = 0.f; o[1] = 0.f; o[2] = 0.f;

        // --- chain: 0 -> 1 -> 2 -> 3 (bones 0,1,2) ---
        euler_rot(ev, 0, Ma);
        px = L[0]*Ma[6]; py = L[0]*Ma[7]; pz = L[0]*Ma[8];
        o[3] = px; o[4] = py; o[5] = pz;
        euler_rot(ev, 1, R); mm3(Ma, R, Mb);
        px += L[1]*Mb[6]; py += L[1]*Mb[7]; pz += L[1]*Mb[8];
        o[6] = px; o[7] = py; o[8] = pz;
        euler_rot(ev, 2, R); mm3(Mb, R, Ma);
        px += L[2]*Ma[6]; py += L[2]*Ma[7]; pz += L[2]*Ma[8];
        o[9] = px; o[10] = py; o[11] = pz;

        // --- chain: 0 -> 4 -> 5 -> 6 (bones 3,4,5) ---
        euler_rot(ev, 3, Ma);
        px = L[3]*Ma[6]; py = L[3]*Ma[7]; pz = L[3]*Ma[8];
        o[12] = px; o[13] = py; o[14] = pz;
        euler_rot(ev, 4, R); mm3(Ma, R, Mb);
        px += L[4]*Mb[6]; py += L[4]*Mb[7]; pz += L[4]*Mb[8];
        o[15] = px; o[16] = py; o[17] = pz;
        euler_rot(ev, 5, R); mm3(Mb, R, Ma);
        px += L[5]*Ma[6]; py += L[5]*Ma[7]; pz += L[5]*Ma[8];
        o[18] = px; o[19] = py; o[20] = pz;

        // --- spine: 0 -> 7 -> 8 (bones 6,7) ---
        euler_rot(ev, 6, Ma);
        px = L[6]*Ma[6]; py = L[6]*Ma[7]; pz = L[6]*Ma[8];
        o[21] = px; o[22] = py; o[23] = pz;
        euler_rot(ev, 7, R); mm3(Ma, R, M8);         // M8 = accum at joint 8
        px += L[7]*M8[6]; py += L[7]*M8[7]; pz += L[7]*M8[8];
        o[24] = px; o[25] = py; o[26] = pz;
        p8x = px; p8y = py; p8z = pz;
    }
    __syncthreads();

    // ---- store phase A: runs of 27 contiguous floats per sample ----
    {
        float* og = out + (size_t)block0 * 51;
        const int tot = nvalid * CA;
        for (int i = tid; i < tot; i += NB) {
            int s = i / CA;              // magic-div (const)
            int j = i - s * CA;
            og[s * 51 + j] = s_o[i];     // LDS stride == CA -> flat index i
        }
    }
    __syncthreads();  // all LDS reads done before phase B overwrites

    // ================= phase B: joints 9..16 =================
    if (tid < nvalid) {
        float* o = s_o + tid * CA;       // keep odd stride 27, use 24 of it
        float Ma[9], Mb[9], R[9];
        float px, py, pz;

        // --- branch: 8 -> 9 -> 10 (bones 8,9) ---
        euler_rot(ev, 8, R); mm3(M8, R, Ma);
        px = p8x + L[8]*Ma[6]; py = p8y + L[8]*Ma[7]; pz = p8z + L[8]*Ma[8];
        o[0] = px; o[1] = py; o[2] = pz;
        euler_rot(ev, 9, R); mm3(Ma, R, Mb);
        px += L[9]*Mb[6]; py += L[9]*Mb[7]; pz += L[9]*Mb[8];
        o[3] = px; o[4] = py; o[5] = pz;

        // --- branch: 8 -> 11 -> 12 -> 13 (bones 10,11,12) ---
        euler_rot(ev, 10, R); mm3(M8, R, Ma);
        px = p8x + L[10]*Ma[6]; py = p8y + L[10]*Ma[7]; pz = p8z + L[10]*Ma[8];
        o[6] = px; o[7] = py; o[8] = pz;
        euler_rot(ev, 11, R); mm3(Ma, R, Mb);
        px += L[11]*Mb[6]; py += L[11]*Mb[7]; pz += L[11]*Mb[8];
        o[9] = px; o[10] = py; o[11] = pz;
        euler_rot(ev, 12, R); mm3(Mb, R, Ma);
        px += L[12]*Ma[6]; py += L[12]*Ma[7]; pz += L[12]*Ma[8];
        o[12] = px; o[13] = py; o[14] = pz;

        // --- branch: 8 -> 14 -> 15 -> 16 (bones 13,14,15) ---
        euler_rot(ev, 13, R); mm3(M8, R, Ma);
        px = p8x + L[13]*Ma[6]; py = p8y + L[13]*Ma[7]; pz = p8z + L[13]*Ma[8];
        o[15] = px; o[16] = py; o[17] = pz;
        euler_rot(ev, 14, R); mm3(Ma, R, Mb);
        px += L[14]*Mb[6]; py += L[14]*Mb[7]; pz += L[14]*Mb[8];
        o[18] = px; o[19] = py; o[20] = pz;
        euler_rot(ev, 15, R); mm3(Mb, R, Ma);
        px += L[15]*Ma[6]; py += L[15]*Ma[7]; pz += L[15]*Ma[8];
        o[21] = px; o[22] = py; o[23] = pz;
    }
    __syncthreads();

    // ---- store phase B: runs of 24 contiguous floats per sample ----
    {
        float* og = out + (size_t)block0 * 51 + CA;
        const int tot = nvalid * CB;
        for (int i = tid; i < tot; i += NB) {
            int s = i / CB;              // magic-div (const)
            int j = i - s * CB;
            og[s * 51 + j] = s_o[s * CA + j];
        }
    }
}

extern "C" void kernel_launch(void* const* d_in, const int* in_sizes, int n_in,
                              void* d_out, int out_size, void* d_ws, size_t ws_size,
                              hipStream_t stream) {
    const float* euler = (const float*)d_in[0];   // (N,16,3) fp32
    const float* blen  = (const float*)d_in[1];   // (N,16,1) fp32
    float* out = (float*)d_out;                   // (N,17,3) fp32

    const int n    = in_sizes[0] / 48;
    const int grid = (n + NB - 1) / NB;
    fk17_kernel<<<grid, NB, 0, stream>>>(euler, blen, out, n);
}